// Round 3
// baseline (262.329 us; speedup 1.0000x reference)
//
#include <hip/hip_runtime.h>

#define HSZ 50        // real hidden units
#define TSZ 512       // timesteps
#define NB  4         // batches per workgroup -> 512 wgs (2 per CU)
#define KPAD 72       // hlds row stride in f16 (144 B, 16B-aligned)

typedef _Float16 half8  __attribute__((ext_vector_type(8)));
typedef float   floatx4 __attribute__((ext_vector_type(4)));

// Activations on pre-scaled arguments (A rows carry the log2e factors):
//   sigmoid gates: y = -log2e * x  ->  sig = rcp(1 + exp2(y))
//   tanh gate:     y = 2*log2e * x ->  tanh = 1 - 2*rcp(1 + exp2(y))
// Robust at extremes: exp2->inf => rcp->0 ; exp2->0 => rcp(1)=1.
__device__ __forceinline__ float sig_y(float y) {
    return __builtin_amdgcn_rcpf(1.0f + __builtin_amdgcn_exp2f(y));
}
__device__ __forceinline__ float tanh_y(float y) {
    return fmaf(-2.0f, __builtin_amdgcn_rcpf(1.0f + __builtin_amdgcn_exp2f(y)), 1.0f);
}

// R12: throughput interleaving. The per-step chain (~920 cy) is ~75% stall
// (MfmaUtil 14%, VALUBusy 46%, LDS ~4%): no resource is the limit, latency
// is. NB=8 ran 1 wg/CU so stalls went unfilled. NB=4 -> 512 wgs = 2
// INDEPENDENT recurrence chains per CU; the HW scheduler fills one chain's
// barrier/LDS/trans stalls with the other's work (wall = 512*chain_eff,
// chain_eff ~0.65-0.8x).
// Mirror generalizes to x4: B cols {n, n+4, n+8, n+12} all replicate batch
// n&3 (h written to 4 mirror rows, off-chain b16 stores). Each lane owns
// exactly ONE (unit,batch) pair: unit 16w+4q+(n>>2), batch n&3 -> per-lane
// activation work halves (10 trans ops), select = 3 cndmasks/gate on own acc.
// Kept: K-augmentation (bias k=50, x_t k=51 -> zero C-input), pre-scaled A
// (exp2-ready MFMA output), 1 barrier/step, f16 h exchange.
__global__ __launch_bounds__(256)
void lstm_mir4(const float* __restrict__ x,
               const float* __restrict__ W_ih,
               const float* __restrict__ W_hh,
               const float* __restrict__ b_ih,
               const float* __restrict__ b_hh,
               const float* __restrict__ W_lin,
               const float* __restrict__ b_lin,
               float* __restrict__ out)
{
    __shared__ float xs[TSZ][NB];                         // x^T [t][n]   (8 KB)
    __shared__ __align__(16) _Float16 hlds[2][16][KPAD];  // aug-h^T dbuf (4.5 KB)

    const int tid = threadIdx.x;
    const int w   = tid >> 6;        // wave id 0..3 -> unit group [16w,16w+16)
    const int ln  = tid & 63;        // lane
    const int n   = ln & 15;         // MFMA column
    const int q   = ln >> 4;         // quad
    const int rr  = n >> 2;          // replica index 0..3 -> unit sub-row
    const int bb  = n & 3;           // real batch this lane activates
    const int b0  = blockIdx.x * NB;

    // --- stage x transposed: global [b][t] -> LDS [t][b] (coalesced) ---
    const float* xg = x + (size_t)b0 * TSZ;
    for (int i = tid; i < NB * TSZ; i += 256)
        xs[i & (TSZ - 1)][i >> 9] = xg[i];
    // --- init h buffers: zero except k==50 slot = 1.0 (both buffers) ---
    for (int i = tid; i < 2 * 16 * KPAD; i += 256)
        ((_Float16*)hlds)[i] = (i % KPAD == 50) ? (_Float16)1.0f : (_Float16)0.0f;

    // --- A fragments: lane holds A[m=16w+n][k=kt*32+q*8+j], augmented and
    //     pre-scaled: k<50 -> W_hh ; k==50 -> b_ih+b_hh ; k==51 -> W_ih.
    //     Row scale: gates i,f,o -> -log2e ; gate g -> +2*log2e.
    const int uA = 16 * w + n;
    half8 af[4][2];
#pragma unroll
    for (int g = 0; g < 4; ++g) {
        const float gs = (g == 2) ? 2.88539008f : -1.44269504f;
        const int row = g * HSZ + uA;
        const bool rok = (uA < HSZ);
#pragma unroll
        for (int kt = 0; kt < 2; ++kt) {
#pragma unroll
            for (int j = 0; j < 8; ++j) {
                const int k = kt * 32 + q * 8 + j;
                float v = 0.0f;
                if (rok) {
                    if (k < HSZ)      v = W_hh[row * HSZ + k];
                    else if (k == 50) v = b_ih[row] + b_hh[row];
                    else if (k == 51) v = W_ih[row];
                }
                af[g][kt][j] = (_Float16)(v * gs);
            }
        }
    }

    float c0 = 0.0f;                 // lane-local cell state (unit u, batch bb)
    __syncthreads();                 // xs + hlds base fill ready
    if (tid < 16)                    // x_0 into buffer 0's aug slot, all rows
        hlds[0][tid][51] = (_Float16)xs[0][tid & 3];
    __syncthreads();

    const floatx4 zero4 = {0.0f, 0.0f, 0.0f, 0.0f};
    // h destination: rows bb, bb+4, bb+8, bb+12 (x4 mirror), col u
    const int u = 16 * w + 4 * q + rr;
    _Float16* const hwp0 = &hlds[0][bb][u];
    _Float16* const hwp1 = &hlds[1][bb][u];
    const bool xl50 = (w == 3) && (q == 0) && (rr == 2);  // unit 50: const 1.0
    const bool xl51 = (w == 3) && (q == 0) && (rr == 3);  // unit 51: x_{t+1}

#pragma unroll 2
    for (int t = 0; t < TSZ; ++t) {
        const int rb = t & 1, wb = rb ^ 1;

        // B fragments: hlds[rb][n][k-contiguous]; cols n,n+4,.. mirror batch n&3
        const half8 bf0 = *(const half8*)&hlds[rb][n][q * 8];
        const half8 bf1 = *(const half8*)&hlds[rb][n][32 + q * 8];

        // Next step's x (wave 3 only; consumed by xl51 lanes at write time).
        float xnext = 0.0f;
        if (w == 3) xnext = xs[(t + 1) & (TSZ - 1)][ln & 3];

        floatx4 acc[4];
#pragma unroll
        for (int g = 0; g < 4; ++g) {
            acc[g] = __builtin_amdgcn_mfma_f32_16x16x32_f16(af[g][0], bf0, zero4,  0, 0, 0);
            acc[g] = __builtin_amdgcn_mfma_f32_16x16x32_f16(af[g][1], bf1, acc[g], 0, 0, 0);
        }

        // Own-register selection: lane's unit is acc row rr (compile-time
        // 2-level cndmask; runtime-indexed vectors would hit scratch).
        float pre[4];
#pragma unroll
        for (int g = 0; g < 4; ++g) {
            const float v01 = (rr & 1) ? acc[g][1] : acc[g][0];
            const float v23 = (rr & 1) ? acc[g][3] : acc[g][2];
            pre[g] = (rr & 2) ? v23 : v01;
        }

        const float i0 = sig_y (pre[0]);
        const float f0 = sig_y (pre[1]);
        const float g0 = tanh_y(pre[2]);
        const float o0 = sig_y (pre[3]);
        c0 = fmaf(f0, c0, i0 * g0);
        float h0 = o0 * tanh_y(c0 * 2.88539008f);
        // pad units (zero A-rows) produce h==0: safe to write.
        // units 50,51 instead carry the augmentation {1.0, x_{t+1}}:
        if (xl50) h0 = 1.0f;
        if (xl51) h0 = xnext;

        const _Float16 hh = (_Float16)h0;
        _Float16* const hw = wb ? hwp1 : hwp0;
        hw[0]         = hh;          // row bb
        hw[4  * KPAD] = hh;          // row bb+4
        hw[8  * KPAD] = hh;          // row bb+8
        hw[12 * KPAD] = hh;          // row bb+12
        __syncthreads();             // h(t) visible for next step's B-read
    }

    // --- epilogue: out[b0+n'] = b_lin + sum_u h_T[u]*W_lin[u]; TSZ even -> buf 0
    if (w == 0 && ln < NB) {
        float acc = b_lin[0];
        for (int uu = 0; uu < HSZ; ++uu)
            acc = fmaf((float)hlds[0][ln][uu], W_lin[uu], acc);
        out[(size_t)b0 + ln] = acc;
    }
}

extern "C" void kernel_launch(void* const* d_in, const int* in_sizes, int n_in,
                              void* d_out, int out_size, void* d_ws, size_t ws_size,
                              hipStream_t stream) {
    const float* x     = (const float*)d_in[0];
    const float* W_ih  = (const float*)d_in[1];
    const float* W_hh  = (const float*)d_in[2];
    const float* b_ih  = (const float*)d_in[3];
    const float* b_hh  = (const float*)d_in[4];
    const float* W_lin = (const float*)d_in[5];
    const float* b_lin = (const float*)d_in[6];
    float* outp = (float*)d_out;

    const int B = in_sizes[0] / TSZ;   // 2048 -> 512 workgroups of 4 batches
    hipLaunchKernelGGL(lstm_mir4, dim3(B / NB), dim3(256), 0, stream,
                       x, W_ih, W_hh, b_ih, b_hh, W_lin, b_lin, outp);
}